// Round 1
// baseline (2327.272 us; speedup 1.0000x reference)
//
#include <hip/hip_runtime.h>

namespace {
constexpr int CS = 16;        // channels
constexpr int XS = 8, YS = 8, US = 256, VS = 256;
constexpr int CH_STRIDE = XS * YS * US * VS;   // 4,194,304 floats per channel

__global__ __launch_bounds__(256) void gs4d_kernel(
    const float* __restrict__ inp, const float* __restrict__ grid,
    float* __restrict__ out, int P)
{
    int p = blockIdx.x * 256 + threadIdx.x;
    if (p >= P) return;

    float4 g = reinterpret_cast<const float4*>(grid)[p];

    // unnormalize, align_corners=True: (g+1)*0.5*(size-1)
    float c0 = (g.x + 1.0f) * 0.5f * (XS - 1);
    float c1 = (g.y + 1.0f) * 0.5f * (YS - 1);
    float c2 = (g.z + 1.0f) * 0.5f * (US - 1);
    float c3 = (g.w + 1.0f) * 0.5f * (VS - 1);

    float f0 = floorf(c0), f1 = floorf(c1), f2 = floorf(c2), f3 = floorf(c3);
    int i0 = (int)f0, i1 = (int)f1, i2 = (int)f2, i3 = (int)f3;
    float t0 = c0 - f0, t1 = c1 - f1, t2 = c2 - f2, t3 = c3 - f3;

    // Per-dim weights (zeroed when index OOB -> padding_mode='zeros')
    // and clipped indices (matches reference: clip then weight*valid).
    float w0[2], w1[2], w2[2], w3[2];
    int   q0[2], q1[2], q2[2], q3[2];
    #pragma unroll
    for (int b = 0; b < 2; ++b) {
        int j;
        j = i0 + b; w0[b] = (b ? t0 : 1.0f - t0) * ((j >= 0 && j < XS) ? 1.0f : 0.0f); q0[b] = min(max(j, 0), XS - 1);
        j = i1 + b; w1[b] = (b ? t1 : 1.0f - t1) * ((j >= 0 && j < YS) ? 1.0f : 0.0f); q1[b] = min(max(j, 0), YS - 1);
        j = i2 + b; w2[b] = (b ? t2 : 1.0f - t2) * ((j >= 0 && j < US) ? 1.0f : 0.0f); q2[b] = min(max(j, 0), US - 1);
        j = i3 + b; w3[b] = (b ? t3 : 1.0f - t3) * ((j >= 0 && j < VS) ? 1.0f : 0.0f); q3[b] = min(max(j, 0), VS - 1);
    }

    // 16 corner flat indices + combined weights
    int   idx[16];
    float w[16];
    #pragma unroll
    for (int bx = 0; bx < 2; ++bx)
    #pragma unroll
    for (int by = 0; by < 2; ++by)
    #pragma unroll
    for (int bu = 0; bu < 2; ++bu)
    #pragma unroll
    for (int bv = 0; bv < 2; ++bv) {
        int k = ((bx * 2 + by) * 2 + bu) * 2 + bv;
        idx[k] = ((q0[bx] * YS + q1[by]) * US + q2[bu]) * VS + q3[bv];
        w[k]   = w0[bx] * w1[by] * w2[bu] * w3[bv];
    }

    // Channel loop: 16 gathered loads + FMAs per channel; coalesced store.
    const float* ip = inp;
    #pragma unroll 4
    for (int c = 0; c < CS; ++c) {
        float acc = 0.0f;
        #pragma unroll
        for (int k = 0; k < 16; ++k) acc = fmaf(w[k], ip[idx[k]], acc);
        out[c * P + p] = acc;
        ip += CH_STRIDE;
    }
}
} // anonymous namespace

extern "C" void kernel_launch(void* const* d_in, const int* in_sizes, int n_in,
                              void* d_out, int out_size, void* d_ws, size_t ws_size,
                              hipStream_t stream) {
    const float* inp  = (const float*)d_in[0];   // [1,16,8,8,256,256] f32
    const float* grid = (const float*)d_in[1];   // [1,P,4] f32
    float* out = (float*)d_out;                  // [1,16,P] f32
    int P = in_sizes[1] / 4;
    int blocks = (P + 255) / 256;
    gs4d_kernel<<<blocks, 256, 0, stream>>>(inp, grid, out, P);
}

// Round 2
// 1534.787 us; speedup vs baseline: 1.5163x; 1.5163x over previous
//
#include <hip/hip_runtime.h>

namespace {
constexpr int CS = 16;        // channels
constexpr int XS = 8, YS = 8, US = 256, VS = 256;
constexpr int CH_STRIDE = XS * YS * US * VS;   // 4,194,304 floats per channel

// One block column per channel (blockIdx.y). Dispatch is x-fastest, so the
// execution front sweeps channel-by-channel: live input working set is one
// 16 MiB channel slice (L3- and mostly L2-resident) instead of 256 MiB.
__global__ __launch_bounds__(256) void gs4d_kernel(
    const float* __restrict__ inp, const float* __restrict__ grid,
    float* __restrict__ out, int P)
{
    int p = blockIdx.x * 256 + threadIdx.x;
    if (p >= P) return;
    int c = blockIdx.y;

    float4 g = reinterpret_cast<const float4*>(grid)[p];

    // unnormalize, align_corners=True: (g+1)*0.5*(size-1)
    float c0 = (g.x + 1.0f) * 0.5f * (XS - 1);
    float c1 = (g.y + 1.0f) * 0.5f * (YS - 1);
    float c2 = (g.z + 1.0f) * 0.5f * (US - 1);
    float c3 = (g.w + 1.0f) * 0.5f * (VS - 1);

    float f0 = floorf(c0), f1 = floorf(c1), f2 = floorf(c2), f3 = floorf(c3);
    int i0 = (int)f0, i1 = (int)f1, i2 = (int)f2, i3 = (int)f3;
    float t0 = c0 - f0, t1 = c1 - f1, t2 = c2 - f2, t3 = c3 - f3;

    // Per-dim weights (zeroed when index OOB -> padding_mode='zeros')
    // and clipped indices (matches reference: clip then weight*valid).
    float w0[2], w1[2], w2[2], w3[2];
    int   q0[2], q1[2], q2[2], q3[2];
    #pragma unroll
    for (int b = 0; b < 2; ++b) {
        int j;
        j = i0 + b; w0[b] = (b ? t0 : 1.0f - t0) * ((j >= 0 && j < XS) ? 1.0f : 0.0f); q0[b] = min(max(j, 0), XS - 1);
        j = i1 + b; w1[b] = (b ? t1 : 1.0f - t1) * ((j >= 0 && j < YS) ? 1.0f : 0.0f); q1[b] = min(max(j, 0), YS - 1);
        j = i2 + b; w2[b] = (b ? t2 : 1.0f - t2) * ((j >= 0 && j < US) ? 1.0f : 0.0f); q2[b] = min(max(j, 0), US - 1);
        j = i3 + b; w3[b] = (b ? t3 : 1.0f - t3) * ((j >= 0 && j < VS) ? 1.0f : 0.0f); q3[b] = min(max(j, 0), VS - 1);
    }

    // 16 corner flat indices + combined weights within this channel's slice.
    const float* ip = inp + (size_t)c * CH_STRIDE;
    float acc = 0.0f;
    #pragma unroll
    for (int bx = 0; bx < 2; ++bx)
    #pragma unroll
    for (int by = 0; by < 2; ++by)
    #pragma unroll
    for (int bu = 0; bu < 2; ++bu)
    #pragma unroll
    for (int bv = 0; bv < 2; ++bv) {
        int idx = ((q0[bx] * YS + q1[by]) * US + q2[bu]) * VS + q3[bv];
        float w = w0[bx] * w1[by] * w2[bu] * w3[bv];
        acc = fmaf(w, ip[idx], acc);
    }

    // Non-temporal store: don't let 64 MB of output evict the input slice.
    __builtin_nontemporal_store(acc, &out[(size_t)c * P + p]);
}
} // anonymous namespace

extern "C" void kernel_launch(void* const* d_in, const int* in_sizes, int n_in,
                              void* d_out, int out_size, void* d_ws, size_t ws_size,
                              hipStream_t stream) {
    const float* inp  = (const float*)d_in[0];   // [1,16,8,8,256,256] f32
    const float* grid = (const float*)d_in[1];   // [1,P,4] f32
    float* out = (float*)d_out;                  // [1,16,P] f32
    int P = in_sizes[1] / 4;
    dim3 blocks((P + 255) / 256, CS);
    gs4d_kernel<<<blocks, 256, 0, stream>>>(inp, grid, out, P);
}

// Round 4
// 394.037 us; speedup vs baseline: 5.9062x; 3.8950x over previous
//
#include <hip/hip_runtime.h>

namespace {
constexpr int CS = 16;        // channels
constexpr int XS = 8, YS = 8, US = 256, VS = 256;
constexpr int CH_STRIDE = XS * YS * US * VS;             // 4,194,304 floats
constexpr size_t TRANS_BYTES = (size_t)CS * CH_STRIDE * 4; // 256 MiB

// ---- Kernel 1: repack [C,X,Y,U,V] -> [X,Y,U,V,C] into ws ------------------
__global__ __launch_bounds__(256) void transpose_kernel(
    const float* __restrict__ inp, float* __restrict__ ws)
{
    __shared__ float lds[CS][257];                 // +1 pad kills bank conflicts
    size_t base = (size_t)blockIdx.x * 256;        // 256 consecutive voxels
    #pragma unroll
    for (int c = 0; c < CS; ++c)                   // coalesced 4B reads per c
        lds[c][threadIdx.x] = inp[(size_t)c * CH_STRIDE + base + threadIdx.x];
    __syncthreads();
    size_t obase = base * CS;
    #pragma unroll
    for (int i = 0; i < CS; ++i) {                 // fully coalesced writes
        int flat = i * 256 + threadIdx.x;          // 0..4095
        ws[obase + flat] = lds[flat & 15][flat >> 4];
    }
}

// ---- helpers ---------------------------------------------------------------
__device__ __forceinline__ void fma4(float4& a, float w, const float4& v) {
    a.x = fmaf(w, v.x, a.x); a.y = fmaf(w, v.y, a.y);
    a.z = fmaf(w, v.z, a.z); a.w = fmaf(w, v.w, a.w);
}

// ---- Kernel 2: gather from [X,Y,U,V,C]; one thread = one point, all 16 ch --
__global__ __launch_bounds__(256) void gather_kernel(
    const float* __restrict__ tin, const float* __restrict__ grid,
    float* __restrict__ out, int P)
{
    int p = blockIdx.x * 256 + threadIdx.x;
    if (p >= P) return;

    float4 g = reinterpret_cast<const float4*>(grid)[p];

    float c0 = (g.x + 1.0f) * 0.5f * (XS - 1);
    float c1 = (g.y + 1.0f) * 0.5f * (YS - 1);
    float c2 = (g.z + 1.0f) * 0.5f * (US - 1);
    float c3 = (g.w + 1.0f) * 0.5f * (VS - 1);

    float f0 = floorf(c0), f1 = floorf(c1), f2 = floorf(c2), f3 = floorf(c3);
    int i0 = (int)f0, i1 = (int)f1, i2 = (int)f2, i3 = (int)f3;
    float t0 = c0 - f0, t1 = c1 - f1, t2 = c2 - f2, t3 = c3 - f3;

    float w0[2], w1[2], w2[2], w3[2];
    int   q0[2], q1[2], q2[2], q3[2];
    #pragma unroll
    for (int b = 0; b < 2; ++b) {
        int j;
        j = i0 + b; w0[b] = (b ? t0 : 1.0f - t0) * ((j >= 0 && j < XS) ? 1.0f : 0.0f); q0[b] = min(max(j, 0), XS - 1);
        j = i1 + b; w1[b] = (b ? t1 : 1.0f - t1) * ((j >= 0 && j < YS) ? 1.0f : 0.0f); q1[b] = min(max(j, 0), YS - 1);
        j = i2 + b; w2[b] = (b ? t2 : 1.0f - t2) * ((j >= 0 && j < US) ? 1.0f : 0.0f); q2[b] = min(max(j, 0), US - 1);
        j = i3 + b; w3[b] = (b ? t3 : 1.0f - t3) * ((j >= 0 && j < VS) ? 1.0f : 0.0f); q3[b] = min(max(j, 0), VS - 1);
    }

    float4 a0 = {0,0,0,0}, a1 = {0,0,0,0}, a2 = {0,0,0,0}, a3 = {0,0,0,0};
    #pragma unroll
    for (int bx = 0; bx < 2; ++bx)
    #pragma unroll
    for (int by = 0; by < 2; ++by) {
        int   xy  = (q0[bx] * YS + q1[by]) << 16;           // * US*VS
        float wxy = w0[bx] * w1[by];
        #pragma unroll
        for (int bu = 0; bu < 2; ++bu) {
            int   xyu  = xy + (q2[bu] << 8);                // * VS
            float wxyu = wxy * w2[bu];
            #pragma unroll
            for (int bv = 0; bv < 2; ++bv) {
                int   vox = xyu + q3[bv];
                float w   = wxyu * w3[bv];
                const float4* cp = reinterpret_cast<const float4*>(tin) + (size_t)vox * 4;
                fma4(a0, w, cp[0]); fma4(a1, w, cp[1]);
                fma4(a2, w, cp[2]); fma4(a3, w, cp[3]);
            }
        }
    }

    float r[16] = {a0.x,a0.y,a0.z,a0.w, a1.x,a1.y,a1.z,a1.w,
                   a2.x,a2.y,a2.z,a2.w, a3.x,a3.y,a3.z,a3.w};
    #pragma unroll
    for (int c = 0; c < CS; ++c)
        __builtin_nontemporal_store(r[c], &out[(size_t)c * P + p]);
}

// ---- Fallback (R2 kernel) if ws is too small -------------------------------
__global__ __launch_bounds__(256) void gs4d_fallback(
    const float* __restrict__ inp, const float* __restrict__ grid,
    float* __restrict__ out, int P)
{
    int p = blockIdx.x * 256 + threadIdx.x;
    if (p >= P) return;
    int c = blockIdx.y;
    float4 g = reinterpret_cast<const float4*>(grid)[p];
    float c0 = (g.x + 1.0f) * 0.5f * (XS - 1);
    float c1 = (g.y + 1.0f) * 0.5f * (YS - 1);
    float c2 = (g.z + 1.0f) * 0.5f * (US - 1);
    float c3 = (g.w + 1.0f) * 0.5f * (VS - 1);
    float f0 = floorf(c0), f1 = floorf(c1), f2 = floorf(c2), f3 = floorf(c3);
    int i0 = (int)f0, i1 = (int)f1, i2 = (int)f2, i3 = (int)f3;
    float t0 = c0 - f0, t1 = c1 - f1, t2 = c2 - f2, t3 = c3 - f3;
    float w0[2], w1[2], w2[2], w3[2];
    int   q0[2], q1[2], q2[2], q3[2];
    #pragma unroll
    for (int b = 0; b < 2; ++b) {
        int j;
        j = i0 + b; w0[b] = (b ? t0 : 1.0f - t0) * ((j >= 0 && j < XS) ? 1.0f : 0.0f); q0[b] = min(max(j, 0), XS - 1);
        j = i1 + b; w1[b] = (b ? t1 : 1.0f - t1) * ((j >= 0 && j < YS) ? 1.0f : 0.0f); q1[b] = min(max(j, 0), YS - 1);
        j = i2 + b; w2[b] = (b ? t2 : 1.0f - t2) * ((j >= 0 && j < US) ? 1.0f : 0.0f); q2[b] = min(max(j, 0), US - 1);
        j = i3 + b; w3[b] = (b ? t3 : 1.0f - t3) * ((j >= 0 && j < VS) ? 1.0f : 0.0f); q3[b] = min(max(j, 0), VS - 1);
    }
    const float* ip = inp + (size_t)c * CH_STRIDE;
    float acc = 0.0f;
    #pragma unroll
    for (int bx = 0; bx < 2; ++bx)
    #pragma unroll
    for (int by = 0; by < 2; ++by)
    #pragma unroll
    for (int bu = 0; bu < 2; ++bu)
    #pragma unroll
    for (int bv = 0; bv < 2; ++bv) {
        int idx = ((q0[bx] * YS + q1[by]) * US + q2[bu]) * VS + q3[bv];
        acc = fmaf(w0[bx] * w1[by] * w2[bu] * w3[bv], ip[idx], acc);
    }
    __builtin_nontemporal_store(acc, &out[(size_t)c * P + p]);
}
} // anonymous namespace

extern "C" void kernel_launch(void* const* d_in, const int* in_sizes, int n_in,
                              void* d_out, int out_size, void* d_ws, size_t ws_size,
                              hipStream_t stream) {
    const float* inp  = (const float*)d_in[0];   // [1,16,8,8,256,256] f32
    const float* grid = (const float*)d_in[1];   // [1,P,4] f32
    float* out = (float*)d_out;                  // [1,16,P] f32
    int P = in_sizes[1] / 4;
    int pblocks = (P + 255) / 256;

    if (ws_size >= TRANS_BYTES) {
        float* ws = (float*)d_ws;
        transpose_kernel<<<CH_STRIDE / 256, 256, 0, stream>>>(inp, ws);
        gather_kernel<<<pblocks, 256, 0, stream>>>(ws, grid, out, P);
    } else {
        dim3 blocks(pblocks, CS);
        gs4d_fallback<<<blocks, 256, 0, stream>>>(inp, grid, out, P);
    }
}